// Round 9
// baseline (66815.625 us; speedup 1.0000x reference)
//
#include <hip/hip_runtime.h>
#include <hip/hip_bf16.h>

typedef unsigned short u16;
typedef unsigned int u32;
typedef unsigned long long u64;
typedef __fp16 f16x2 __attribute__((ext_vector_type(2)));

// ---------- sizes ----------
#define T_  8192
#define F_  1024
#define H_  2048
#define G_  8192   // 4*H

#define NREG  32    // exchange regions (one per producer lane 0..31)
#define DSLOT 4     // ring depth (dataflow skew bound 1; 4 for margin)

// ws layout (bytes). Total ~178 MB.
#define WS_XG    0                    // bf16 [T][G]          134217728
#define WS_ABF   134217728ull         // bf16 [T][F]           16777216
#define WS_WBF   150994944ull         // bf16 [G][F]           16777216
#define WS_HX    167772160ull         // u32 [32][4][2048]      1048576
#define WS_PART  168820736ull         // f32 [T][256]           8388608

static __device__ __forceinline__ float bf2f(u16 u) {
    union { u32 i; float f; } x; x.i = ((u32)u) << 16; return x.f;
}
static __device__ __forceinline__ u16 f2bf(float f) {
    union { float f; u32 u; } x; x.f = f;
    u32 r = (x.u + 0x7fffu + ((x.u >> 16) & 1u)) >> 16;
    return (u16)r;
}

// ---------- fp32 -> bf16 convert (4 elems/thread) ----------
__global__ void cvt4_kernel(const float* __restrict__ s, u16* __restrict__ d, int n4) {
    int i = blockIdx.x * 256 + threadIdx.x;
    if (i < n4) {
        float4 v = ((const float4*)s)[i];
        union { u16 h[4]; uint2 v2; } o;
        o.h[0] = f2bf(v.x); o.h[1] = f2bf(v.y); o.h[2] = f2bf(v.z); o.h[3] = f2bf(v.w);
        ((uint2*)d)[i] = o.v2;
    }
}

// ---------- x_gates GEMM: xg[t][g] = sum_f A[t][f]*W[g][f] + b_ih[g]+b_hh[g] ----------
__global__ __launch_bounds__(256) void gemm_xg_kernel(
    const u16* __restrict__ A, const u16* __restrict__ W,
    const float* __restrict__ b_ih, const float* __restrict__ b_hh,
    u16* __restrict__ xg)
{
    __shared__ u16 As[64][40];
    __shared__ u16 Ws[64][40];

    const int tb = blockIdx.y * 64;
    const int gb = blockIdx.x * 64;
    const int tid  = threadIdx.x;
    const int wave = tid >> 6;
    const int lane = tid & 63;
    const int m    = lane & 15;
    const int quad = lane >> 4;

    const int lrow = tid >> 2;
    const int lcol = (tid & 3) * 8;

    using frag  = __attribute__((ext_vector_type(8))) short;
    using f32x4 = __attribute__((ext_vector_type(4))) float;
    f32x4 acc[4] = {};

    for (int k0 = 0; k0 < F_; k0 += 32) {
        __syncthreads();
        *(uint4*)&As[lrow][lcol] = *(const uint4*)&A[(size_t)(tb + lrow) * F_ + k0 + lcol];
        *(uint4*)&Ws[lrow][lcol] = *(const uint4*)&W[(size_t)(gb + lrow) * F_ + k0 + lcol];
        __syncthreads();
        frag bfr = *(const frag*)&Ws[wave * 16 + m][quad * 8];
#pragma unroll
        for (int i = 0; i < 4; ++i) {
            frag afr = *(const frag*)&As[i * 16 + m][quad * 8];
            acc[i] = __builtin_amdgcn_mfma_f32_16x16x32_bf16(afr, bfr, acc[i], 0, 0, 0);
        }
    }
    const int g = gb + wave * 16 + m;
    const float bias = b_ih[g] + b_hh[g];
#pragma unroll
    for (int i = 0; i < 4; ++i)
#pragma unroll
        for (int r = 0; r < 4; ++r) {
            int t = tb + i * 16 + quad * 4 + r;
            xg[(size_t)t * G_ + g] = f2bf(acc[i][r] + bias);
        }
}

// ---------- persistent LSTM recurrence: immediate-publish tagged exchange ----------
// 256 blocks x 512 threads. Wave w owns hidden unit uu = b*8+w.
// All 64 lanes hold the full gate sums after the shfl_xor butterfly, so every
// lane redundantly computes the cell update (c replicated, deterministic) and
// lanes 0..31 publish [f16(h)<<16 | tag16=t] u32 words straight to 32 regions —
// no LDS hop, no pre-publish barrier. Consumers poll 4 words (2 independent u64
// loads, ONE retry loop), bit-repack into LDS f16x2, one barrier per step.
// Safety: hs2 overwrite is publish-gated — a wave passes its poll only after
// every block (incl. its own siblings) published h_t, i.e. finished reading hs2.
__global__ __launch_bounds__(512, 2) void lstm_rec_kernel(
    const float* __restrict__ Whh,   // [G][H] f32
    const u16*  __restrict__ xg,     // [T][G] bf16
    const float* __restrict__ Wout,  // [H]
    u32*  __restrict__ hx,           // [32][4][2048] u32, pre-filled 0xFF
    float* __restrict__ part)        // [T][256]
{
    __shared__ u32 hs2[H_ / 2];      // h as packed f16x2 (pair p = units 2p,2p+1)
    __shared__ float pl[2][8];       // parity-buffered per-wave Wout partials

    const int b   = blockIdx.x;
    const int tid = threadIdx.x;
    const int w   = tid >> 6;
    const int l   = tid & 63;
    const int uu  = b * 8 + w;          // hidden unit (wave-uniform)

    // weights (f16): wreg[r][4c+j] covers h-pair p = 4l + 256c + j of gate row r
    // (pair layout chosen so compute reads hs2[4l..4l+3] as ds_read_b128)
    f16x2 wreg[4][16];
#pragma unroll
    for (int r = 0; r < 4; ++r) {
        const float* wrow = Whh + (size_t)(r * H_ + uu) * H_;
#pragma unroll
        for (int c = 0; c < 4; ++c)
#pragma unroll
            for (int j = 0; j < 4; ++j) {
                float2 v = *(const float2*)&wrow[8 * l + 512 * c + 2 * j];
                wreg[r][4 * c + j] = __builtin_amdgcn_cvt_pkrtz(v.x, v.y);
            }
    }
    const float wout = Wout[uu];
    float c_ = 0.f;                     // cell state, replicated in all lanes

    // h_{-1} = 0
    hs2[tid] = 0; hs2[tid + 512] = 0;
    __syncthreads();

    // xg pipeline regs (ALL lanes load the same 4 values — broadcast)
    float xgi, xgf, xgg, xgo;
    {
        const u16* xr = &xg[uu];
        xgi = bf2f(xr[0]); xgf = bf2f(xr[2048]);
        xgg = bf2f(xr[4096]); xgo = bf2f(xr[6144]);
    }

    const u32* mypoll = hx + (size_t)((b & (NREG - 1)) * DSLOT) * 2048;

    for (int t = 0; t < T_; ++t) {
        // prefetch next step's xg (a full step of slack)
        float nxi = 0.f, nxf = 0.f, nxg = 0.f, nxo = 0.f;
        if (t + 1 < T_) {
            const u16* xr = &xg[(size_t)(t + 1) * G_ + uu];
            nxi = bf2f(xr[0]); nxf = bf2f(xr[2048]);
            nxg = bf2f(xr[4096]); nxo = bf2f(xr[6144]);
        }

        float a0 = 0.f, a1 = 0.f, a2 = 0.f, a3 = 0.f;
#pragma unroll
        for (int c = 0; c < 4; ++c) {
            union { uint4 q; u32 s[4]; } hq;
            hq.q = *(const uint4*)&hs2[4 * l + 256 * c];
#pragma unroll
            for (int j = 0; j < 4; ++j) {
                union { u32 u; f16x2 h; } hw;
                hw.u = hq.s[j];
                a0 = __builtin_amdgcn_fdot2(wreg[0][4 * c + j], hw.h, a0, false);
                a1 = __builtin_amdgcn_fdot2(wreg[1][4 * c + j], hw.h, a1, false);
                a2 = __builtin_amdgcn_fdot2(wreg[2][4 * c + j], hw.h, a2, false);
                a3 = __builtin_amdgcn_fdot2(wreg[3][4 * c + j], hw.h, a3, false);
            }
        }
#pragma unroll
        for (int off = 32; off >= 1; off >>= 1) {
            a0 += __shfl_xor(a0, off);
            a1 += __shfl_xor(a1, off);
            a2 += __shfl_xor(a2, off);
            a3 += __shfl_xor(a3, off);
        }

        // cell update in ALL lanes (identical inputs -> identical results)
        const int slot = t & (DSLOT - 1);
        {
            float gi = a0 + xgi, gf = a1 + xgf, gg = a2 + xgg, go = a3 + xgo;
            float i_ = 1.f / (1.f + __expf(-gi));
            float f_ = 1.f / (1.f + __expf(-gf));
            float g_ = 1.f - 2.f / (__expf(2.f * gg) + 1.f);   // tanh
            float o_ = 1.f / (1.f + __expf(-go));
            c_ = fmaf(f_, c_, i_ * g_);
            float th = 1.f - 2.f / (__expf(2.f * c_) + 1.f);   // tanh
            float hval = o_ * th;

            // immediate publish: lane l<32 stores [f16(h)|t] to region l
            union { f16x2 h; u32 u; } pk;
            pk.h = __builtin_amdgcn_cvt_pkrtz(hval, hval);
            u32 word = (pk.u << 16) | (u32)t;
            if (l < NREG)
                __hip_atomic_store(&hx[(size_t)((l * DSLOT + slot)) * 2048 + uu], word,
                                   __ATOMIC_RELAXED, __HIP_MEMORY_SCOPE_AGENT);
            if (l == 0) pl[t & 1][w] = hval * wout;
        }
        xgi = nxi; xgf = nxf; xgg = nxg; xgo = nxo;

        // poll h_t: thread tid owns words [4tid, 4tid+4) — 2 INDEPENDENT u64
        // loads in one retry loop (single cadence). Word = [f16|tag16].
        {
            const u64* q = (const u64*)(mypoll + (size_t)slot * 2048) + 2 * tid;
            const u32 tg = (u32)t;
            u64 v0, v1;
            do {
                v0 = __hip_atomic_load(q,     __ATOMIC_RELAXED, __HIP_MEMORY_SCOPE_AGENT);
                v1 = __hip_atomic_load(q + 1, __ATOMIC_RELAXED, __HIP_MEMORY_SCOPE_AGENT);
            } while (((u32)v0 & 0xFFFFu) != tg || ((u32)(v0 >> 32) & 0xFFFFu) != tg ||
                     ((u32)v1 & 0xFFFFu) != tg || ((u32)(v1 >> 32) & 0xFFFFu) != tg);
            hs2[2 * tid]     = ((u32)(v0 >> 16) & 0xFFFFu) | ((u32)(v0 >> 48) << 16);
            hs2[2 * tid + 1] = ((u32)(v1 >> 16) & 0xFFFFu) | ((u32)(v1 >> 48) << 16);
        }
        __syncthreads();   // hs2 = h_t complete for all waves

        if (tid == 511) {
            const float* p = pl[t & 1];
            part[(size_t)t * 256 + b] = p[0] + p[1] + p[2] + p[3]
                                      + p[4] + p[5] + p[6] + p[7];
        }
    }
}

// ---------- final: out[t] = b_out + sum_b part[t][b] ----------
__global__ __launch_bounds__(256) void out_reduce_kernel(
    const float* __restrict__ part, const float* __restrict__ b_out,
    float* __restrict__ out)
{
    int t = blockIdx.x * 4 + (threadIdx.x >> 6);
    int l = threadIdx.x & 63;
    const float* p = &part[(size_t)t * 256];
    float s = p[l] + p[l + 64] + p[l + 128] + p[l + 192];
#pragma unroll
    for (int off = 32; off >= 1; off >>= 1) s += __shfl_down(s, off);
    if (l == 0) out[t] = s + b_out[0];
}

extern "C" void kernel_launch(void* const* d_in, const int* in_sizes, int n_in,
                              void* d_out, int out_size, void* d_ws, size_t ws_size,
                              hipStream_t stream) {
    const float* input = (const float*)d_in[0];
    const float* W_ih  = (const float*)d_in[1];
    const float* W_hh  = (const float*)d_in[2];
    const float* b_ih  = (const float*)d_in[3];
    const float* b_hh  = (const float*)d_in[4];
    const float* W_out = (const float*)d_in[5];
    const float* b_out = (const float*)d_in[6];
    float* out = (float*)d_out;

    char* ws = (char*)d_ws;
    u16*   xg   = (u16*)(ws + WS_XG);
    u16*   Abf  = (u16*)(ws + WS_ABF);
    u16*   Wbf  = (u16*)(ws + WS_WBF);
    u32*   hx   = (u32*)(ws + WS_HX);
    float* part = (float*)(ws + WS_PART);

    // tag bytes init to 0xFFFF (never equals any t in [0,8192))
    (void)hipMemsetAsync(hx, 0xFF, (size_t)NREG * DSLOT * 2048 * sizeof(u32), stream);

    const int n4 = (T_ * F_) / 4;
    cvt4_kernel<<<(n4 + 255) / 256, 256, 0, stream>>>(input, Abf, n4);
    cvt4_kernel<<<(G_ * F_ / 4 + 255) / 256, 256, 0, stream>>>(W_ih, Wbf, G_ * F_ / 4);

    gemm_xg_kernel<<<dim3(G_ / 64, T_ / 64), 256, 0, stream>>>(Abf, Wbf, b_ih, b_hh, xg);

    lstm_rec_kernel<<<256, 512, 0, stream>>>(W_hh, xg, W_out, hx, part);

    out_reduce_kernel<<<T_ / 4, 256, 0, stream>>>(part, b_out, out);
}